// Round 4
// baseline (219.325 us; speedup 1.0000x reference)
//
#include <hip/hip_runtime.h>
#include <cstdint>
#include <cstddef>

#define NEG 0.2f
#define CAP 10752          // padded per-bucket capacity (mean 8192, +28 sigma)
#define FINE_CAP CAP

typedef __attribute__((ext_vector_type(8))) short short8;   // 8 bf16 (4 VGPR)
typedef __attribute__((ext_vector_type(4))) float f32x4;    // MFMA acc
typedef __attribute__((ext_vector_type(2))) float f32x2;    // packed FMA pair

// ---------------------------------------------------------------------------
// bf16 helpers (RNE)
// ---------------------------------------------------------------------------
__device__ __forceinline__ unsigned short f2bf(float f) {
  unsigned u = __float_as_uint(f);
  unsigned r = (u + 0x7fffu + ((u >> 16) & 1u)) >> 16;
  return (unsigned short)r;
}

// ---------------------------------------------------------------------------
// Edge dtype sniff + cursor init + W transpose to bf16 Wt[col][k] (one block).
// ---------------------------------------------------------------------------
__global__ __launch_bounds__(512) void k_detect(const int* __restrict__ ei32,
                                                int* __restrict__ flag,
                                                int* __restrict__ cursor,
                                                const float* __restrict__ W,
                                                unsigned short* __restrict__ Wt) {
  int t = threadIdx.x;                 // 512 threads
  cursor[t] = t * CAP;
  if (t < 64) {
    int v = ei32[2 * t + 1];
    unsigned long long b = __ballot(v != 0);
    if (t == 0) flag[0] = (b == 0ULL) ? 1 : 0;   // 1 = int64, 0 = int32
  }
  // transpose 128x128 W (f32, row-major [k][c]) -> Wt bf16 [c][k]
#pragma unroll
  for (int i = 0; i < 8; ++i) {
    int idx = i * 512 + t;             // float4 index, 4096 total
    float4 v = ((const float4*)W)[idx];
    int k = idx >> 5;                  // 32 float4 per row
    int c = (idx & 31) * 4;
    Wt[(c + 0) * 128 + k] = f2bf(v.x);
    Wt[(c + 1) * 128 + k] = f2bf(v.y);
    Wt[(c + 2) * 128 + k] = f2bf(v.z);
    Wt[(c + 3) * 128 + k] = f2bf(v.w);
  }
}

__device__ __forceinline__ int edge_val(const void* ei, long long idx, int is64) {
  return is64 ? (int)((const long long*)ei)[idx] : ((const int*)ei)[idx];
}

// ---------------------------------------------------------------------------
// FUSED gemm (MFMA, no LDS) + msplit (4KB LDS) kernel, 256 threads both roles.
// Ms blocks at gid%3==0 (k-th ms block at gid=3k): coverage requires
// 3*(nms-1) < grid, guaranteed by grid = max(ngemm+nms, 3*nms-2).
// gemm_id = gid - min(gid/3+1, nms) is bijective and sequential; surplus gemm
// blocks beyond ngemm are fully guarded.
//
// gemm role (4 waves x 16 rows): h = x @ W via mfma_f32_16x16x32_bf16, f32
// accumulate. Epilogue: bf16 h + a_s/a_d dots.
//
// ms role: scatter packed records (dst&255)<<17|src into padded coarse
// buckets (bucket = dst>>8), 4096 edges/block, LDS hist for ranks, one
// global atomic per nonzero bin.
// ---------------------------------------------------------------------------
#define MS_CHUNK 4096
__global__ __launch_bounds__(256) void k_fused(
    const float* __restrict__ x, const unsigned short* __restrict__ Wt,
    const float* __restrict__ as_, const float* __restrict__ ad_,
    unsigned short* __restrict__ hb, float* __restrict__ a_s,
    float* __restrict__ a_d, int N,
    const void* __restrict__ ei, const int* __restrict__ flag,
    int* __restrict__ cursor, uint32_t* __restrict__ buck, int E, int nms) {
  __shared__ int hist[512];
  __shared__ int resv[512];
  int gid = blockIdx.x;
  int t = threadIdx.x;
  bool is_ms = ((gid % 3) == 0) && ((gid / 3) < nms);

  if (is_ms) {
    // ---------------- msplit ----------------
    int bid = gid / 3;
    const int is64 = flag[0];
    for (int i = t; i < 512; i += 256) hist[i] = 0;
    __syncthreads();
    long long base = (long long)bid * MS_CHUNK;
    uint32_t rec[16];
    int bb[16], rk[16];
#pragma unroll
    for (int i = 0; i < 16; ++i) {
      long long idx = base + i * 256 + t;
      bb[i] = -1;
      if (idx < E) {
        int s = edge_val(ei, idx, is64);
        int d = edge_val(ei, (long long)E + idx, is64);
        bb[i] = d >> 8;
        rec[i] = ((uint32_t)(d & 255) << 17) | (uint32_t)s;
        rk[i] = atomicAdd(&hist[bb[i]], 1);
      }
    }
    __syncthreads();
    for (int b = t; b < 512; b += 256) {
      int c = hist[b];
      resv[b] = c ? atomicAdd(&cursor[b], c) : 0;
    }
    __syncthreads();
#pragma unroll
    for (int i = 0; i < 16; ++i) {
      if (bb[i] >= 0) buck[(size_t)resv[bb[i]] + rk[i]] = rec[i];
    }
    return;
  }

  // ---------------- gemm (MFMA) ----------------
  int gemm_id = gid - min(gid / 3 + 1, nms);
  int lane = t & 63;
  int wv = t >> 6;                         // 4 waves
  int row0 = gemm_id * 64 + wv * 16;
  int r = lane & 15, o = lane >> 4;

  int arow = row0 + r;
  if (arow >= N) arow = N - 1;
  const float* xr = x + (size_t)arow * 128 + o * 8;
  short8 a[4];
#pragma unroll
  for (int kt = 0; kt < 4; ++kt) {
    float4 lo = *(const float4*)(xr + kt * 32);
    float4 hi = *(const float4*)(xr + kt * 32 + 4);
    short8 av;
    av[0] = (short)f2bf(lo.x); av[1] = (short)f2bf(lo.y);
    av[2] = (short)f2bf(lo.z); av[3] = (short)f2bf(lo.w);
    av[4] = (short)f2bf(hi.x); av[5] = (short)f2bf(hi.y);
    av[6] = (short)f2bf(hi.z); av[7] = (short)f2bf(hi.w);
    a[kt] = av;
  }

  float ats[8], atd[8];
#pragma unroll
  for (int ct = 0; ct < 8; ++ct) {
    ats[ct] = as_[ct * 16 + r];
    atd[ct] = ad_[ct * 16 + r];
  }

  f32x4 acc[8];
#pragma unroll
  for (int ct = 0; ct < 8; ++ct) acc[ct] = (f32x4){0.f, 0.f, 0.f, 0.f};
#pragma unroll
  for (int ct = 0; ct < 8; ++ct) {
    const unsigned short* wb = Wt + ((size_t)(ct * 16 + r)) * 128 + o * 8;
#pragma unroll
    for (int kt = 0; kt < 4; ++kt) {
      short8 b = *(const short8*)(wb + kt * 32);
      acc[ct] = __builtin_amdgcn_mfma_f32_16x16x32_bf16(a[kt], b, acc[ct], 0, 0, 0);
    }
  }

#pragma unroll
  for (int j = 0; j < 4; ++j) {
    int row = row0 + o * 4 + j;
    bool ok = row < N;
    float ps = 0.f, pd = 0.f;
#pragma unroll
    for (int ct = 0; ct < 8; ++ct) {
      float v = acc[ct][j];
      if (ok) hb[(size_t)row * 128 + ct * 16 + r] = f2bf(v);
      ps += v * ats[ct];
      pd += v * atd[ct];
    }
#pragma unroll
    for (int d = 1; d <= 8; d <<= 1) {
      ps += __shfl_xor(ps, d);
      pd += __shfl_xor(pd, d);
    }
    if (ok && r == 0) { a_s[row] = ps; a_d[row] = pd; }
  }
}

// ---------------------------------------------------------------------------
// Fine sort within each bucket: offsets + CSR packed (src, expw) records
//   sw[e] = { src, bits(exp(leaky_relu(a_s[src] + a_d[dst]))) }
// 1024 threads/block (R13 occupancy fix). R16: k_bscan merged in — each
// block recomputes the 512-wide exclusive scan of bucket counts locally
// (cursor[] is L2-hot, scan is ~free) and picks element b. Removes one
// kernel launch + dependency gap.
// ---------------------------------------------------------------------------
__global__ __launch_bounds__(1024) void k_fine(const int* __restrict__ cursor,
                                               const uint32_t* __restrict__ buck,
                                               const float* __restrict__ a_s,
                                               const float* __restrict__ a_d,
                                               int* __restrict__ offsets,
                                               int2* __restrict__ sw,
                                               int N, int E) {
  __shared__ int hist[256];
  __shared__ int cur[256];
  __shared__ int wsum8[8];
  __shared__ int wsum[4];
  __shared__ float ad_sh[256];
  __shared__ int b0_sh;
  __shared__ uint32_t stage[FINE_CAP];
  int b = blockIdx.x;
  int t = threadIdx.x;
  int lane = t & 63;
  int cnt = cursor[b] - b * CAP;
  const uint32_t* bk = buck + (size_t)b * CAP;
  int node = (b << 8) + (t & 255);

  // local 512-wide exclusive scan of bucket counts -> b0 (element b)
  int sv = 0, sincl = 0, sw8 = t >> 6;
  if (t < 512) {
    sv = cursor[t] - t * CAP;
    sincl = sv;
#pragma unroll
    for (int d = 1; d < 64; d <<= 1) {
      int o = __shfl_up(sincl, d);
      if (lane >= d) sincl += o;
    }
    if (lane == 63) wsum8[sw8] = sincl;
  }
  if (t < 256) {
    hist[t] = 0;
    ad_sh[t] = (node < N) ? a_d[node] : 0.f;
  }
  __syncthreads();
  if (t < 512) {
    int woff = 0;
    for (int i = 0; i < sw8; ++i) woff += wsum8[i];
    int excl = woff + sincl - sv;
    if (t == b) b0_sh = excl;
  }
  __syncthreads();
  int b0 = b0_sh;

  for (int i = t; i < cnt; i += 1024) atomicAdd(&hist[bk[i] >> 17], 1);
  __syncthreads();
  int v = 0, incl = 0;
  int w4 = t >> 6;
  if (t < 256) {
    v = hist[t];
    incl = v;
#pragma unroll
    for (int d = 1; d < 64; d <<= 1) {
      int o = __shfl_up(incl, d);
      if (lane >= d) incl += o;
    }
    if (lane == 63) wsum[w4] = incl;
  }
  __syncthreads();
  if (t < 256) {
    int woff = 0;
    for (int i = 0; i < w4; ++i) woff += wsum[i];
    int excl = woff + incl - v;
    cur[t] = excl;
    if (node < N) offsets[node] = b0 + excl;
  }
  if (b == 0 && t == 0) offsets[N] = E;
  __syncthreads();
  for (int i = t; i < cnt; i += 1024) {
    uint32_t r = bk[i];
    int pos = atomicAdd(&cur[r >> 17], 1);
    stage[pos] = r;
  }
  __syncthreads();
  for (int i = t; i < cnt; i += 1024) {
    uint32_t r = stage[i];
    int s = (int)(r & 0x1ffffu);
    float e = a_s[s] + ad_sh[r >> 17];
    e = (e > 0.f) ? e : NEG * e;
    sw[b0 + i] = make_int2(s, __float_as_int(__expf(e)));
  }
}

// ---------------------------------------------------------------------------
// Per-node weighted feature gather. One wave per node, 4 nodes per block;
// 4 groups of 16 lanes -> 4 edges in flight, lane loads 16B of the 256B
// bf16 row.
// R16: shfl-broadcast meta replaced with direct broadcast loads (16 lanes
// of a group load the SAME 8-B sw record -> L1-hot, HW-broadcast). This
// deletes the per-stage ds_bpermute x2 + lgkm round-trip from the gather
// dependency chain. Meta prefetched one rotation ahead (meta->gather dep
// spans ~7 outstanding loads). Sum accumulated from stage weights: each
// edge counted exactly 16x (once per lane of its group), divided out at
// the end. FMA in float2 packed form (v_pk_fma_f32 eligible).
// History: depth4/40VGPR=107us; depth8/72VGPR=136us (>64 cliff); depth5/
// 44VGPR=108us (depth-insensitive -> wave-level MLP not the constraint).
// ---------------------------------------------------------------------------
#define AGG_META(K, JJ)                                                   \
  {                                                                       \
    int e_ = (JJ) * 4 + g;                                                \
    m##K = swp[(e_ < cnt) ? e_ : 0];                                      \
    if (e_ >= cnt) m##K.y = 0;   /* w = 0.0f for pipeline dummies */      \
  }

#define AGG_GATH(K)                                                       \
  {                                                                       \
    w##K = __int_as_float(m##K.y);                                        \
    sum += w##K;                                                          \
    u##K = *(const uint4*)&hb[(size_t)(uint32_t)m##K.x * 128 + l16 * 8];  \
  }

#define AGG_FMA(K)                                                        \
  {                                                                       \
    f32x2 ww; ww[0] = w##K; ww[1] = w##K;                                 \
    f32x2 p;                                                              \
    p[0] = __uint_as_float(u##K.x << 16);                                 \
    p[1] = __uint_as_float(u##K.x & 0xffff0000u);                         \
    acc2[0] += ww * p;                                                    \
    p[0] = __uint_as_float(u##K.y << 16);                                 \
    p[1] = __uint_as_float(u##K.y & 0xffff0000u);                         \
    acc2[1] += ww * p;                                                    \
    p[0] = __uint_as_float(u##K.z << 16);                                 \
    p[1] = __uint_as_float(u##K.z & 0xffff0000u);                         \
    acc2[2] += ww * p;                                                    \
    p[0] = __uint_as_float(u##K.w << 16);                                 \
    p[1] = __uint_as_float(u##K.w & 0xffff0000u);                         \
    acc2[3] += ww * p;                                                    \
  }

__global__ __launch_bounds__(256) void k_agg(const int* __restrict__ offs,
                                             const int2* __restrict__ sw,
                                             const unsigned short* __restrict__ hb,
                                             const float* __restrict__ bias,
                                             float* __restrict__ out, int N) {
  int lane = threadIdx.x & 63;
  int n = blockIdx.x * 4 + (threadIdx.x >> 6);
  if (n >= N) return;
  int g = lane >> 4;        // edge group 0..3
  int l16 = lane & 15;      // 16B slot within the 256B row
  f32x2 acc2[4];
#pragma unroll
  for (int i = 0; i < 4; ++i) { acc2[i][0] = 0.f; acc2[i][1] = 0.f; }
  float sum = 0.f;
  int s0 = offs[n], s1 = offs[n + 1];

  for (int base = s0; base < s1; base += 64) {
    const int2* swp = sw + base;
    int cnt = min(64, s1 - base);
    int iters = (cnt + 3) >> 2;
    int2 m0, m1, m2, m3;
    uint4 u0, u1, u2, u3;
    float w0, w1, w2, w3;
    AGG_META(0, 0) AGG_META(1, 1) AGG_META(2, 2) AGG_META(3, 3)
    AGG_GATH(0) AGG_META(0, 4)
    AGG_GATH(1) AGG_META(1, 5)
    AGG_GATH(2) AGG_META(2, 6)
    AGG_GATH(3) AGG_META(3, 7)
    int j = 0;
    for (; j + 4 < iters; j += 4) {
      AGG_FMA(0) AGG_GATH(0) AGG_META(0, j + 8)
      AGG_FMA(1) AGG_GATH(1) AGG_META(1, j + 9)
      AGG_FMA(2) AGG_GATH(2) AGG_META(2, j + 10)
      AGG_FMA(3) AGG_GATH(3) AGG_META(3, j + 11)
    }
    AGG_FMA(0) AGG_FMA(1) AGG_FMA(2) AGG_FMA(3)
  }
#pragma unroll
  for (int d = 1; d <= 32; d <<= 1) sum += __shfl_xor(sum, d);
#pragma unroll
  for (int d = 16; d <= 32; d <<= 1) {
#pragma unroll
    for (int i = 0; i < 4; ++i) {
      acc2[i][0] += __shfl_xor(acc2[i][0], d);
      acc2[i][1] += __shfl_xor(acc2[i][1], d);
    }
  }
  sum *= 0.0625f;                       // each edge's w counted 16x
  float inv = 1.0f / (sum + 1e-16f);
  if (lane < 32) {
    int half = g & 1;                   // 0 for lanes 0-15, 1 for 16-31
    int f = l16 * 8 + half * 4;
    float4 bv = *(const float4*)&bias[f];
    float4 o;
    o.x = fmaxf(acc2[half * 2 + 0][0] * inv + bv.x, 0.f);
    o.y = fmaxf(acc2[half * 2 + 0][1] * inv + bv.y, 0.f);
    o.z = fmaxf(acc2[half * 2 + 1][0] * inv + bv.z, 0.f);
    o.w = fmaxf(acc2[half * 2 + 1][1] * inv + bv.w, 0.f);
    *(float4*)&out[(size_t)n * 128 + f] = o;
  }
}

// ---------------------------------------------------------------------------
extern "C" void kernel_launch(void* const* d_in, const int* in_sizes, int n_in,
                              void* d_out, int out_size, void* d_ws, size_t ws_size,
                              hipStream_t stream) {
  const float* x = (const float*)d_in[0];
  const void* ei = d_in[1];
  const float* W = (const float*)d_in[2];
  const float* att_s = (const float*)d_in[3];
  const float* att_d = (const float*)d_in[4];
  const float* bias = (const float*)d_in[5];
  float* out = (float*)d_out;

  const int N = in_sizes[0] / 128;
  const int E = in_sizes[1] / 2;
  const int NB = (N + 255) >> 8;      // coarse buckets (<=512 for N<=131072)

  uint8_t* ws = (uint8_t*)d_ws;
  size_t off = 0;
  auto alloc = [&](size_t bytes) -> void* {
    void* p = ws + off;
    off = (off + bytes + 511) & ~(size_t)511;
    return p;
  };
  int* flag = (int*)alloc(4);
  int* bcur = (int*)alloc(512 * 4);
  unsigned short* Wt = (unsigned short*)alloc(128 * 128 * 2);
  int* offsets = (int*)alloc((size_t)(N + 1) * 4);
  int2* sw = (int2*)alloc((size_t)E * 8);
  unsigned short* hb = (unsigned short*)alloc((size_t)N * 128 * 2);
  float* a_s = (float*)alloc((size_t)N * 4);
  float* a_d = (float*)alloc((size_t)N * 4);
  // Padded bucket scratch lives in d_out: dead until k_agg, which fully
  // rewrites out for every node afterwards (deterministic across replays).
  uint32_t* buck = (uint32_t*)d_out;   // NB*CAP*4 <= 17MB <= out 51.2MB
  (void)ws_size; (void)n_in; (void)out_size;

  const int ngemm = (N + 63) / 64;
  const int nms = (E + MS_CHUNK - 1) / MS_CHUNK;
  int grid = ngemm + nms;
  if (grid < 3 * nms - 2) grid = 3 * nms - 2;   // ms coverage: 3*(nms-1) < grid

  k_detect<<<1, 512, 0, stream>>>((const int*)ei, flag, bcur, W, Wt);
  k_fused<<<grid, 256, 0, stream>>>(x, Wt, att_s, att_d, hb, a_s, a_d, N,
                                    ei, flag, bcur, buck, E, nms);
  k_fine<<<NB, 1024, 0, stream>>>(bcur, buck, a_s, a_d, offsets, sw, N, E);
  k_agg<<<(N + 3) / 4, 256, 0, stream>>>(offsets, sw, hb, bias, out, N);
}

// Round 5
// 200.790 us; speedup vs baseline: 1.0923x; 1.0923x over previous
//
#include <hip/hip_runtime.h>
#include <cstdint>
#include <cstddef>

#define NEG 0.2f
#define CAP 10752          // padded per-bucket capacity (mean 8192, +28 sigma)
#define FINE_CAP CAP

typedef __attribute__((ext_vector_type(8))) short short8;   // 8 bf16 (4 VGPR)
typedef __attribute__((ext_vector_type(4))) float f32x4;    // MFMA acc

// ---------------------------------------------------------------------------
// bf16 helpers (RNE)
// ---------------------------------------------------------------------------
__device__ __forceinline__ unsigned short f2bf(float f) {
  unsigned u = __float_as_uint(f);
  unsigned r = (u + 0x7fffu + ((u >> 16) & 1u)) >> 16;
  return (unsigned short)r;
}

// ---------------------------------------------------------------------------
// Edge dtype sniff + cursor init + W transpose to bf16 Wt[col][k] (one block).
// ---------------------------------------------------------------------------
__global__ __launch_bounds__(512) void k_detect(const int* __restrict__ ei32,
                                                int* __restrict__ flag,
                                                int* __restrict__ cursor,
                                                const float* __restrict__ W,
                                                unsigned short* __restrict__ Wt) {
  int t = threadIdx.x;                 // 512 threads
  cursor[t] = t * CAP;
  if (t < 64) {
    int v = ei32[2 * t + 1];
    unsigned long long b = __ballot(v != 0);
    if (t == 0) flag[0] = (b == 0ULL) ? 1 : 0;   // 1 = int64, 0 = int32
  }
  // transpose 128x128 W (f32, row-major [k][c]) -> Wt bf16 [c][k]
#pragma unroll
  for (int i = 0; i < 8; ++i) {
    int idx = i * 512 + t;             // float4 index, 4096 total
    float4 v = ((const float4*)W)[idx];
    int k = idx >> 5;                  // 32 float4 per row
    int c = (idx & 31) * 4;
    Wt[(c + 0) * 128 + k] = f2bf(v.x);
    Wt[(c + 1) * 128 + k] = f2bf(v.y);
    Wt[(c + 2) * 128 + k] = f2bf(v.z);
    Wt[(c + 3) * 128 + k] = f2bf(v.w);
  }
}

__device__ __forceinline__ int edge_val(const void* ei, long long idx, int is64) {
  return is64 ? (int)((const long long*)ei)[idx] : ((const int*)ei)[idx];
}

// ---------------------------------------------------------------------------
// FUSED gemm (MFMA, no LDS) + msplit (4KB LDS) kernel, 256 threads both roles.
// Ms blocks at gid%3==0 (k-th ms block at gid=3k): coverage requires
// 3*(nms-1) < grid, guaranteed by grid = max(ngemm+nms, 3*nms-2).
// gemm_id = gid - min(gid/3+1, nms) is bijective and sequential; surplus gemm
// blocks beyond ngemm are fully guarded.
//
// gemm role (4 waves x 16 rows): h = x @ W via mfma_f32_16x16x32_bf16, f32
// accumulate. Epilogue: bf16 h + a_s/a_d dots.
//
// ms role: scatter packed records (dst&255)<<17|src into padded coarse
// buckets (bucket = dst>>8), 4096 edges/block, LDS hist for ranks, one
// global atomic per nonzero bin.
// ---------------------------------------------------------------------------
#define MS_CHUNK 4096
__global__ __launch_bounds__(256) void k_fused(
    const float* __restrict__ x, const unsigned short* __restrict__ Wt,
    const float* __restrict__ as_, const float* __restrict__ ad_,
    unsigned short* __restrict__ hb, float* __restrict__ a_s,
    float* __restrict__ a_d, int N,
    const void* __restrict__ ei, const int* __restrict__ flag,
    int* __restrict__ cursor, uint32_t* __restrict__ buck, int E, int nms) {
  __shared__ int hist[512];
  __shared__ int resv[512];
  int gid = blockIdx.x;
  int t = threadIdx.x;
  bool is_ms = ((gid % 3) == 0) && ((gid / 3) < nms);

  if (is_ms) {
    // ---------------- msplit ----------------
    int bid = gid / 3;
    const int is64 = flag[0];
    for (int i = t; i < 512; i += 256) hist[i] = 0;
    __syncthreads();
    long long base = (long long)bid * MS_CHUNK;
    uint32_t rec[16];
    int bb[16], rk[16];
#pragma unroll
    for (int i = 0; i < 16; ++i) {
      long long idx = base + i * 256 + t;
      bb[i] = -1;
      if (idx < E) {
        int s = edge_val(ei, idx, is64);
        int d = edge_val(ei, (long long)E + idx, is64);
        bb[i] = d >> 8;
        rec[i] = ((uint32_t)(d & 255) << 17) | (uint32_t)s;
        rk[i] = atomicAdd(&hist[bb[i]], 1);
      }
    }
    __syncthreads();
    for (int b = t; b < 512; b += 256) {
      int c = hist[b];
      resv[b] = c ? atomicAdd(&cursor[b], c) : 0;
    }
    __syncthreads();
#pragma unroll
    for (int i = 0; i < 16; ++i) {
      if (bb[i] >= 0) buck[(size_t)resv[bb[i]] + rk[i]] = rec[i];
    }
    return;
  }

  // ---------------- gemm (MFMA) ----------------
  int gemm_id = gid - min(gid / 3 + 1, nms);
  int lane = t & 63;
  int wv = t >> 6;                         // 4 waves
  int row0 = gemm_id * 64 + wv * 16;
  int r = lane & 15, o = lane >> 4;

  int arow = row0 + r;
  if (arow >= N) arow = N - 1;
  const float* xr = x + (size_t)arow * 128 + o * 8;
  short8 a[4];
#pragma unroll
  for (int kt = 0; kt < 4; ++kt) {
    float4 lo = *(const float4*)(xr + kt * 32);
    float4 hi = *(const float4*)(xr + kt * 32 + 4);
    short8 av;
    av[0] = (short)f2bf(lo.x); av[1] = (short)f2bf(lo.y);
    av[2] = (short)f2bf(lo.z); av[3] = (short)f2bf(lo.w);
    av[4] = (short)f2bf(hi.x); av[5] = (short)f2bf(hi.y);
    av[6] = (short)f2bf(hi.z); av[7] = (short)f2bf(hi.w);
    a[kt] = av;
  }

  float ats[8], atd[8];
#pragma unroll
  for (int ct = 0; ct < 8; ++ct) {
    ats[ct] = as_[ct * 16 + r];
    atd[ct] = ad_[ct * 16 + r];
  }

  f32x4 acc[8];
#pragma unroll
  for (int ct = 0; ct < 8; ++ct) acc[ct] = (f32x4){0.f, 0.f, 0.f, 0.f};
#pragma unroll
  for (int ct = 0; ct < 8; ++ct) {
    const unsigned short* wb = Wt + ((size_t)(ct * 16 + r)) * 128 + o * 8;
#pragma unroll
    for (int kt = 0; kt < 4; ++kt) {
      short8 b = *(const short8*)(wb + kt * 32);
      acc[ct] = __builtin_amdgcn_mfma_f32_16x16x32_bf16(a[kt], b, acc[ct], 0, 0, 0);
    }
  }

#pragma unroll
  for (int j = 0; j < 4; ++j) {
    int row = row0 + o * 4 + j;
    bool ok = row < N;
    float ps = 0.f, pd = 0.f;
#pragma unroll
    for (int ct = 0; ct < 8; ++ct) {
      float v = acc[ct][j];
      if (ok) hb[(size_t)row * 128 + ct * 16 + r] = f2bf(v);
      ps += v * ats[ct];
      pd += v * atd[ct];
    }
#pragma unroll
    for (int d = 1; d <= 8; d <<= 1) {
      ps += __shfl_xor(ps, d);
      pd += __shfl_xor(pd, d);
    }
    if (ok && r == 0) { a_s[row] = ps; a_d[row] = pd; }
  }
}

// ---------------------------------------------------------------------------
// Fine sort within each bucket: offsets + CSR packed (src, expw) records
//   sw[e] = { src, bits(exp(leaky_relu(a_s[src] + a_d[dst]))) }
// 1024 threads/block (occupancy fix). k_bscan merged in: each block
// recomputes the 512-wide exclusive scan of bucket counts locally
// (cursor[] is L2-hot, scan is ~free) and picks element b. Removes one
// kernel launch + dependency gap. [R4: passed, rest-of-pipeline ~88us]
// ---------------------------------------------------------------------------
__global__ __launch_bounds__(1024) void k_fine(const int* __restrict__ cursor,
                                               const uint32_t* __restrict__ buck,
                                               const float* __restrict__ a_s,
                                               const float* __restrict__ a_d,
                                               int* __restrict__ offsets,
                                               int2* __restrict__ sw,
                                               int N, int E) {
  __shared__ int hist[256];
  __shared__ int cur[256];
  __shared__ int wsum8[8];
  __shared__ int wsum[4];
  __shared__ float ad_sh[256];
  __shared__ int b0_sh;
  __shared__ uint32_t stage[FINE_CAP];
  int b = blockIdx.x;
  int t = threadIdx.x;
  int lane = t & 63;
  int cnt = cursor[b] - b * CAP;
  const uint32_t* bk = buck + (size_t)b * CAP;
  int node = (b << 8) + (t & 255);

  // local 512-wide exclusive scan of bucket counts -> b0 (element b)
  int sv = 0, sincl = 0, sw8 = t >> 6;
  if (t < 512) {
    sv = cursor[t] - t * CAP;
    sincl = sv;
#pragma unroll
    for (int d = 1; d < 64; d <<= 1) {
      int o = __shfl_up(sincl, d);
      if (lane >= d) sincl += o;
    }
    if (lane == 63) wsum8[sw8] = sincl;
  }
  if (t < 256) {
    hist[t] = 0;
    ad_sh[t] = (node < N) ? a_d[node] : 0.f;
  }
  __syncthreads();
  if (t < 512) {
    int woff = 0;
    for (int i = 0; i < sw8; ++i) woff += wsum8[i];
    int excl = woff + sincl - sv;
    if (t == b) b0_sh = excl;
  }
  __syncthreads();
  int b0 = b0_sh;

  for (int i = t; i < cnt; i += 1024) atomicAdd(&hist[bk[i] >> 17], 1);
  __syncthreads();
  int v = 0, incl = 0;
  int w4 = t >> 6;
  if (t < 256) {
    v = hist[t];
    incl = v;
#pragma unroll
    for (int d = 1; d < 64; d <<= 1) {
      int o = __shfl_up(incl, d);
      if (lane >= d) incl += o;
    }
    if (lane == 63) wsum[w4] = incl;
  }
  __syncthreads();
  if (t < 256) {
    int woff = 0;
    for (int i = 0; i < w4; ++i) woff += wsum[i];
    int excl = woff + incl - v;
    cur[t] = excl;
    if (node < N) offsets[node] = b0 + excl;
  }
  if (b == 0 && t == 0) offsets[N] = E;
  __syncthreads();
  for (int i = t; i < cnt; i += 1024) {
    uint32_t r = bk[i];
    int pos = atomicAdd(&cur[r >> 17], 1);
    stage[pos] = r;
  }
  __syncthreads();
  for (int i = t; i < cnt; i += 1024) {
    uint32_t r = stage[i];
    int s = (int)(r & 0x1ffffu);
    float e = a_s[s] + ad_sh[r >> 17];
    e = (e > 0.f) ? e : NEG * e;
    sw[b0 + i] = make_int2(s, __float_as_int(__expf(e)));
  }
}

// ---------------------------------------------------------------------------
// Per-node weighted feature gather — REVERTED to the proven R3 form
// (shfl meta, depth 5, 44 VGPR, 108us measured).
// Model (R0-R4 evidence): k_agg is bound by the per-CU vector-memory miss
// path: each edge needs 2 x 128B line fills; E*2 = 6.4M lines at the
// implied ~0.1 line/cy/CU service rate (~40 outstanding misses x ~400cy
// mixed L2/L3 latency) -> ~104us floor. Confirmed by: depth 4/5 identical
// (107/108), half waves only -22% (R1), +VMEM instrs regress (R4: meta as
// broadcast loads, 17->32 instr/chunk, 108->131us). Do not add VMEM
// instructions; do not cross the 64-VGPR cliff; do not clamp min-waves
// (R2: forced 32 VGPR -> 1.19GB scratch spill, 400us).
// ---------------------------------------------------------------------------
#define AGG_LOAD(K, JJ)                                                   \
  {                                                                       \
    int e_ = ((JJ) * 4 + g) & 63;                                         \
    int ss_ = __shfl(s_l, e_);                                            \
    float ww_ = __shfl(w_l, e_);                                          \
    w##K = ((JJ) < iters) ? ww_ : 0.f;                                    \
    u##K = *(const uint4*)&hb[(size_t)ss_ * 128 + l16 * 8];               \
  }

#define AGG_FMA(K)                                                        \
  {                                                                       \
    acc[0] += w##K * __uint_as_float(u##K.x << 16);                       \
    acc[1] += w##K * __uint_as_float(u##K.x & 0xffff0000u);               \
    acc[2] += w##K * __uint_as_float(u##K.y << 16);                       \
    acc[3] += w##K * __uint_as_float(u##K.y & 0xffff0000u);               \
    acc[4] += w##K * __uint_as_float(u##K.z << 16);                       \
    acc[5] += w##K * __uint_as_float(u##K.z & 0xffff0000u);               \
    acc[6] += w##K * __uint_as_float(u##K.w << 16);                       \
    acc[7] += w##K * __uint_as_float(u##K.w & 0xffff0000u);               \
  }

__global__ __launch_bounds__(256) void k_agg(const int* __restrict__ offs,
                                             const int2* __restrict__ sw,
                                             const unsigned short* __restrict__ hb,
                                             const float* __restrict__ bias,
                                             float* __restrict__ out, int N) {
  int lane = threadIdx.x & 63;
  int n = blockIdx.x * 4 + (threadIdx.x >> 6);
  if (n >= N) return;
  int g = lane >> 4;        // edge group 0..3
  int l16 = lane & 15;      // 16B slot within the 256B row
  float acc[8] = {};
  float sum = 0.f;
  int s0 = offs[n], s1 = offs[n + 1];

  for (int base = s0; base < s1; base += 64) {
    int idx = base + lane;
    int s_l = 0;
    float w_l = 0.f;
    if (idx < s1) {
      int2 m = sw[idx];
      s_l = m.x;
      w_l = __int_as_float(m.y);
    }
    sum += w_l;
    int cnt = min(64, s1 - base);
    int iters = (cnt + 3) >> 2;
    uint4 u0, u1, u2, u3, u4;
    float w0, w1, w2, w3, w4;
    AGG_LOAD(0, 0) AGG_LOAD(1, 1) AGG_LOAD(2, 2)
    AGG_LOAD(3, 3) AGG_LOAD(4, 4)
    int j = 0;
    for (; j + 5 < iters; j += 5) {
      AGG_FMA(0) AGG_LOAD(0, j + 5)
      AGG_FMA(1) AGG_LOAD(1, j + 6)
      AGG_FMA(2) AGG_LOAD(2, j + 7)
      AGG_FMA(3) AGG_LOAD(3, j + 8)
      AGG_FMA(4) AGG_LOAD(4, j + 9)
    }
    AGG_FMA(0) AGG_FMA(1) AGG_FMA(2) AGG_FMA(3) AGG_FMA(4)
  }
#pragma unroll
  for (int d = 1; d <= 32; d <<= 1) sum += __shfl_xor(sum, d);
#pragma unroll
  for (int d = 16; d <= 32; d <<= 1) {
#pragma unroll
    for (int i = 0; i < 8; ++i) acc[i] += __shfl_xor(acc[i], d);
  }
  float inv = 1.0f / (sum + 1e-16f);
  if (lane < 32) {
    int half = g & 1;                     // 0 for lanes 0-15, 1 for 16-31
    int f = l16 * 8 + half * 4;
    float4 bv = *(const float4*)&bias[f];
    float4 o;
    o.x = fmaxf(acc[half * 4 + 0] * inv + bv.x, 0.f);
    o.y = fmaxf(acc[half * 4 + 1] * inv + bv.y, 0.f);
    o.z = fmaxf(acc[half * 4 + 2] * inv + bv.z, 0.f);
    o.w = fmaxf(acc[half * 4 + 3] * inv + bv.w, 0.f);
    *(float4*)&out[(size_t)n * 128 + f] = o;
  }
}

// ---------------------------------------------------------------------------
extern "C" void kernel_launch(void* const* d_in, const int* in_sizes, int n_in,
                              void* d_out, int out_size, void* d_ws, size_t ws_size,
                              hipStream_t stream) {
  const float* x = (const float*)d_in[0];
  const void* ei = d_in[1];
  const float* W = (const float*)d_in[2];
  const float* att_s = (const float*)d_in[3];
  const float* att_d = (const float*)d_in[4];
  const float* bias = (const float*)d_in[5];
  float* out = (float*)d_out;

  const int N = in_sizes[0] / 128;
  const int E = in_sizes[1] / 2;
  const int NB = (N + 255) >> 8;      // coarse buckets (<=512 for N<=131072)

  uint8_t* ws = (uint8_t*)d_ws;
  size_t off = 0;
  auto alloc = [&](size_t bytes) -> void* {
    void* p = ws + off;
    off = (off + bytes + 511) & ~(size_t)511;
    return p;
  };
  int* flag = (int*)alloc(4);
  int* bcur = (int*)alloc(512 * 4);
  unsigned short* Wt = (unsigned short*)alloc(128 * 128 * 2);
  int* offsets = (int*)alloc((size_t)(N + 1) * 4);
  int2* sw = (int2*)alloc((size_t)E * 8);
  unsigned short* hb = (unsigned short*)alloc((size_t)N * 128 * 2);
  float* a_s = (float*)alloc((size_t)N * 4);
  float* a_d = (float*)alloc((size_t)N * 4);
  // Padded bucket scratch lives in d_out: dead until k_agg, which fully
  // rewrites out for every node afterwards (deterministic across replays).
  uint32_t* buck = (uint32_t*)d_out;   // NB*CAP*4 <= 17MB <= out 51.2MB
  (void)ws_size; (void)n_in; (void)out_size;

  const int ngemm = (N + 63) / 64;
  const int nms = (E + MS_CHUNK - 1) / MS_CHUNK;
  int grid = ngemm + nms;
  if (grid < 3 * nms - 2) grid = 3 * nms - 2;   // ms coverage: 3*(nms-1) < grid

  k_detect<<<1, 512, 0, stream>>>((const int*)ei, flag, bcur, W, Wt);
  k_fused<<<grid, 256, 0, stream>>>(x, Wt, att_s, att_d, hb, a_s, a_d, N,
                                    ei, flag, bcur, buck, E, nms);
  k_fine<<<NB, 1024, 0, stream>>>(bcur, buck, a_s, a_d, offsets, sw, N, E);
  k_agg<<<(N + 3) / 4, 256, 0, stream>>>(offsets, sw, hb, bias, out, N);
}

// Round 6
// 190.890 us; speedup vs baseline: 1.1490x; 1.0519x over previous
//
#include <hip/hip_runtime.h>
#include <cstdint>
#include <cstddef>

#define NEG 0.2f
#define CAP 10752          // padded per-bucket capacity (mean 8192, +28 sigma)
#define FINE_CAP CAP

typedef __attribute__((ext_vector_type(8))) short short8;   // 8 bf16 (4 VGPR)
typedef __attribute__((ext_vector_type(4))) float f32x4;    // MFMA acc

// ---------------------------------------------------------------------------
// bf16 helpers (RNE)
// ---------------------------------------------------------------------------
__device__ __forceinline__ unsigned short f2bf(float f) {
  unsigned u = __float_as_uint(f);
  unsigned r = (u + 0x7fffu + ((u >> 16) & 1u)) >> 16;
  return (unsigned short)r;
}

// ---------------------------------------------------------------------------
// Edge dtype sniff + cursor init + W transpose to bf16 Wt[col][k] (one block).
// ---------------------------------------------------------------------------
__global__ __launch_bounds__(512) void k_detect(const int* __restrict__ ei32,
                                                int* __restrict__ flag,
                                                int* __restrict__ cursor,
                                                const float* __restrict__ W,
                                                unsigned short* __restrict__ Wt) {
  int t = threadIdx.x;                 // 512 threads
  cursor[t] = t * CAP;
  if (t < 64) {
    int v = ei32[2 * t + 1];
    unsigned long long b = __ballot(v != 0);
    if (t == 0) flag[0] = (b == 0ULL) ? 1 : 0;   // 1 = int64, 0 = int32
  }
  // transpose 128x128 W (f32, row-major [k][c]) -> Wt bf16 [c][k]
#pragma unroll
  for (int i = 0; i < 8; ++i) {
    int idx = i * 512 + t;             // float4 index, 4096 total
    float4 v = ((const float4*)W)[idx];
    int k = idx >> 5;                  // 32 float4 per row
    int c = (idx & 31) * 4;
    Wt[(c + 0) * 128 + k] = f2bf(v.x);
    Wt[(c + 1) * 128 + k] = f2bf(v.y);
    Wt[(c + 2) * 128 + k] = f2bf(v.z);
    Wt[(c + 3) * 128 + k] = f2bf(v.w);
  }
}

__device__ __forceinline__ int edge_val(const void* ei, long long idx, int is64) {
  return is64 ? (int)((const long long*)ei)[idx] : ((const int*)ei)[idx];
}

// ---------------------------------------------------------------------------
// FUSED gemm (MFMA, no LDS) + msplit (4KB LDS) kernel, 256 threads both roles.
// Ms blocks at gid%3==0 (k-th ms block at gid=3k): coverage requires
// 3*(nms-1) < grid, guaranteed by grid = max(ngemm+nms, 3*nms-2).
// gemm_id = gid - min(gid/3+1, nms) is bijective and sequential; surplus gemm
// blocks beyond ngemm are fully guarded.
//
// gemm role (4 waves x 16 rows): h = x @ W via mfma_f32_16x16x32_bf16, f32
// accumulate. Epilogue: bf16 h + a_s/a_d dots.
//
// ms role: scatter packed records (dst&255)<<17|src into padded coarse
// buckets (bucket = dst>>8), 4096 edges/block, LDS hist for ranks, one
// global atomic per nonzero bin.
// ---------------------------------------------------------------------------
#define MS_CHUNK 4096
__global__ __launch_bounds__(256) void k_fused(
    const float* __restrict__ x, const unsigned short* __restrict__ Wt,
    const float* __restrict__ as_, const float* __restrict__ ad_,
    unsigned short* __restrict__ hb, float* __restrict__ a_s,
    float* __restrict__ a_d, int N,
    const void* __restrict__ ei, const int* __restrict__ flag,
    int* __restrict__ cursor, uint32_t* __restrict__ buck, int E, int nms) {
  __shared__ int hist[512];
  __shared__ int resv[512];
  int gid = blockIdx.x;
  int t = threadIdx.x;
  bool is_ms = ((gid % 3) == 0) && ((gid / 3) < nms);

  if (is_ms) {
    // ---------------- msplit ----------------
    int bid = gid / 3;
    const int is64 = flag[0];
    for (int i = t; i < 512; i += 256) hist[i] = 0;
    __syncthreads();
    long long base = (long long)bid * MS_CHUNK;
    uint32_t rec[16];
    int bb[16], rk[16];
#pragma unroll
    for (int i = 0; i < 16; ++i) {
      long long idx = base + i * 256 + t;
      bb[i] = -1;
      if (idx < E) {
        int s = edge_val(ei, idx, is64);
        int d = edge_val(ei, (long long)E + idx, is64);
        bb[i] = d >> 8;
        rec[i] = ((uint32_t)(d & 255) << 17) | (uint32_t)s;
        rk[i] = atomicAdd(&hist[bb[i]], 1);
      }
    }
    __syncthreads();
    for (int b = t; b < 512; b += 256) {
      int c = hist[b];
      resv[b] = c ? atomicAdd(&cursor[b], c) : 0;
    }
    __syncthreads();
#pragma unroll
    for (int i = 0; i < 16; ++i) {
      if (bb[i] >= 0) buck[(size_t)resv[bb[i]] + rk[i]] = rec[i];
    }
    return;
  }

  // ---------------- gemm (MFMA) ----------------
  int gemm_id = gid - min(gid / 3 + 1, nms);
  int lane = t & 63;
  int wv = t >> 6;                         // 4 waves
  int row0 = gemm_id * 64 + wv * 16;
  int r = lane & 15, o = lane >> 4;

  int arow = row0 + r;
  if (arow >= N) arow = N - 1;
  const float* xr = x + (size_t)arow * 128 + o * 8;
  short8 a[4];
#pragma unroll
  for (int kt = 0; kt < 4; ++kt) {
    float4 lo = *(const float4*)(xr + kt * 32);
    float4 hi = *(const float4*)(xr + kt * 32 + 4);
    short8 av;
    av[0] = (short)f2bf(lo.x); av[1] = (short)f2bf(lo.y);
    av[2] = (short)f2bf(lo.z); av[3] = (short)f2bf(lo.w);
    av[4] = (short)f2bf(hi.x); av[5] = (short)f2bf(hi.y);
    av[6] = (short)f2bf(hi.z); av[7] = (short)f2bf(hi.w);
    a[kt] = av;
  }

  float ats[8], atd[8];
#pragma unroll
  for (int ct = 0; ct < 8; ++ct) {
    ats[ct] = as_[ct * 16 + r];
    atd[ct] = ad_[ct * 16 + r];
  }

  f32x4 acc[8];
#pragma unroll
  for (int ct = 0; ct < 8; ++ct) acc[ct] = (f32x4){0.f, 0.f, 0.f, 0.f};
#pragma unroll
  for (int ct = 0; ct < 8; ++ct) {
    const unsigned short* wb = Wt + ((size_t)(ct * 16 + r)) * 128 + o * 8;
#pragma unroll
    for (int kt = 0; kt < 4; ++kt) {
      short8 b = *(const short8*)(wb + kt * 32);
      acc[ct] = __builtin_amdgcn_mfma_f32_16x16x32_bf16(a[kt], b, acc[ct], 0, 0, 0);
    }
  }

#pragma unroll
  for (int j = 0; j < 4; ++j) {
    int row = row0 + o * 4 + j;
    bool ok = row < N;
    float ps = 0.f, pd = 0.f;
#pragma unroll
    for (int ct = 0; ct < 8; ++ct) {
      float v = acc[ct][j];
      if (ok) hb[(size_t)row * 128 + ct * 16 + r] = f2bf(v);
      ps += v * ats[ct];
      pd += v * atd[ct];
    }
#pragma unroll
    for (int d = 1; d <= 8; d <<= 1) {
      ps += __shfl_xor(ps, d);
      pd += __shfl_xor(pd, d);
    }
    if (ok && r == 0) { a_s[row] = ps; a_d[row] = pd; }
  }
}

// ---------------------------------------------------------------------------
// Fine sort within each bucket -> offsets + fine-sorted RAW 4B records.
// R6: no exp / no sw int2 output. The sorted stage[] (packed
// (dst&255)<<17|src) is written out verbatim (12.8MB vs 25.6MB); the
// softmax weight is recomputed on the fly in k_agg from a_s/a_d (L2-hot).
// Deletes per-edge a_s gathers + __expf from this kernel entirely.
// 1024 threads/block (occupancy fix); k_bscan merged (local 512-scan).
// ---------------------------------------------------------------------------
__global__ __launch_bounds__(1024) void k_fine(const int* __restrict__ cursor,
                                               const uint32_t* __restrict__ buck,
                                               int* __restrict__ offsets,
                                               uint32_t* __restrict__ fsr,
                                               int N, int E) {
  __shared__ int hist[256];
  __shared__ int cur[256];
  __shared__ int wsum8[8];
  __shared__ int wsum[4];
  __shared__ int b0_sh;
  __shared__ uint32_t stage[FINE_CAP];
  int b = blockIdx.x;
  int t = threadIdx.x;
  int lane = t & 63;
  int cnt = cursor[b] - b * CAP;
  const uint32_t* bk = buck + (size_t)b * CAP;
  int node = (b << 8) + (t & 255);

  // local 512-wide exclusive scan of bucket counts -> b0 (element b)
  int sv = 0, sincl = 0, sw8 = t >> 6;
  if (t < 512) {
    sv = cursor[t] - t * CAP;
    sincl = sv;
#pragma unroll
    for (int d = 1; d < 64; d <<= 1) {
      int o = __shfl_up(sincl, d);
      if (lane >= d) sincl += o;
    }
    if (lane == 63) wsum8[sw8] = sincl;
  }
  if (t < 256) hist[t] = 0;
  __syncthreads();
  if (t < 512) {
    int woff = 0;
    for (int i = 0; i < sw8; ++i) woff += wsum8[i];
    int excl = woff + sincl - sv;
    if (t == b) b0_sh = excl;
  }
  __syncthreads();
  int b0 = b0_sh;

  for (int i = t; i < cnt; i += 1024) atomicAdd(&hist[bk[i] >> 17], 1);
  __syncthreads();
  int v = 0, incl = 0;
  int w4 = t >> 6;
  if (t < 256) {
    v = hist[t];
    incl = v;
#pragma unroll
    for (int d = 1; d < 64; d <<= 1) {
      int o = __shfl_up(incl, d);
      if (lane >= d) incl += o;
    }
    if (lane == 63) wsum[w4] = incl;
  }
  __syncthreads();
  if (t < 256) {
    int woff = 0;
    for (int i = 0; i < w4; ++i) woff += wsum[i];
    int excl = woff + incl - v;
    cur[t] = excl;
    if (node < N) offsets[node] = b0 + excl;
  }
  if (b == 0 && t == 0) offsets[N] = E;
  __syncthreads();
  for (int i = t; i < cnt; i += 1024) {
    uint32_t r = bk[i];
    int pos = atomicAdd(&cur[r >> 17], 1);
    stage[pos] = r;
  }
  __syncthreads();
  for (int i = t; i < cnt; i += 1024) fsr[b0 + i] = stage[i];
}

// ---------------------------------------------------------------------------
// Per-node weighted feature gather — proven R3/R5 core loop (shfl meta,
// depth 5, 44 VGPR). R6: the meta phase reads the 4B raw record and
// recomputes w = exp(leaky(a_s[src] + a_d[n])) on the fly. a_s is 400KB
// (fully L2-resident), a_d[n] is one scalar per node. Adds 1 L2-hot VMEM
// + ~8 VALU per 64-edge chunk; halves the streamed meta bytes.
// Model (R0-R5): k_agg is bound by the per-CU vector-memory miss path
// (~104us floor: E*2 128B line fills at ~0.1 line/cy/CU). Do not add
// line-missing VMEM; do not cross the 64-VGPR cliff; do not clamp
// min-waves (R2: forced 32 VGPR -> 1.19GB scratch spill).
// ---------------------------------------------------------------------------
#define AGG_LOAD(K, JJ)                                                   \
  {                                                                       \
    int e_ = ((JJ) * 4 + g) & 63;                                         \
    int ss_ = __shfl(s_l, e_);                                            \
    float ww_ = __shfl(w_l, e_);                                          \
    w##K = ((JJ) < iters) ? ww_ : 0.f;                                    \
    u##K = *(const uint4*)&hb[(size_t)ss_ * 128 + l16 * 8];               \
  }

#define AGG_FMA(K)                                                        \
  {                                                                       \
    acc[0] += w##K * __uint_as_float(u##K.x << 16);                       \
    acc[1] += w##K * __uint_as_float(u##K.x & 0xffff0000u);               \
    acc[2] += w##K * __uint_as_float(u##K.y << 16);                       \
    acc[3] += w##K * __uint_as_float(u##K.y & 0xffff0000u);               \
    acc[4] += w##K * __uint_as_float(u##K.z << 16);                       \
    acc[5] += w##K * __uint_as_float(u##K.z & 0xffff0000u);               \
    acc[6] += w##K * __uint_as_float(u##K.w << 16);                       \
    acc[7] += w##K * __uint_as_float(u##K.w & 0xffff0000u);               \
  }

__global__ __launch_bounds__(256) void k_agg(const int* __restrict__ offs,
                                             const uint32_t* __restrict__ fsr,
                                             const float* __restrict__ a_s,
                                             const float* __restrict__ a_d,
                                             const unsigned short* __restrict__ hb,
                                             const float* __restrict__ bias,
                                             float* __restrict__ out, int N) {
  int lane = threadIdx.x & 63;
  int n = blockIdx.x * 4 + (threadIdx.x >> 6);
  if (n >= N) return;
  int g = lane >> 4;        // edge group 0..3
  int l16 = lane & 15;      // 16B slot within the 256B row
  float acc[8] = {};
  float sum = 0.f;
  int s0 = offs[n], s1 = offs[n + 1];
  float adn = a_d[n];

  for (int base = s0; base < s1; base += 64) {
    int idx = base + lane;
    int s_l = 0;
    float w_l = 0.f;
    if (idx < s1) {
      uint32_t r = fsr[idx];
      s_l = (int)(r & 0x1ffffu);
      float e = a_s[s_l] + adn;
      e = (e > 0.f) ? e : NEG * e;
      w_l = __expf(e);
    }
    sum += w_l;
    int cnt = min(64, s1 - base);
    int iters = (cnt + 3) >> 2;
    uint4 u0, u1, u2, u3, u4;
    float w0, w1, w2, w3, w4;
    AGG_LOAD(0, 0) AGG_LOAD(1, 1) AGG_LOAD(2, 2)
    AGG_LOAD(3, 3) AGG_LOAD(4, 4)
    int j = 0;
    for (; j + 5 < iters; j += 5) {
      AGG_FMA(0) AGG_LOAD(0, j + 5)
      AGG_FMA(1) AGG_LOAD(1, j + 6)
      AGG_FMA(2) AGG_LOAD(2, j + 7)
      AGG_FMA(3) AGG_LOAD(3, j + 8)
      AGG_FMA(4) AGG_LOAD(4, j + 9)
    }
    AGG_FMA(0) AGG_FMA(1) AGG_FMA(2) AGG_FMA(3) AGG_FMA(4)
  }
#pragma unroll
  for (int d = 1; d <= 32; d <<= 1) sum += __shfl_xor(sum, d);
#pragma unroll
  for (int d = 16; d <= 32; d <<= 1) {
#pragma unroll
    for (int i = 0; i < 8; ++i) acc[i] += __shfl_xor(acc[i], d);
  }
  float inv = 1.0f / (sum + 1e-16f);
  if (lane < 32) {
    int half = g & 1;                     // 0 for lanes 0-15, 1 for 16-31
    int f = l16 * 8 + half * 4;
    float4 bv = *(const float4*)&bias[f];
    float4 o;
    o.x = fmaxf(acc[half * 4 + 0] * inv + bv.x, 0.f);
    o.y = fmaxf(acc[half * 4 + 1] * inv + bv.y, 0.f);
    o.z = fmaxf(acc[half * 4 + 2] * inv + bv.z, 0.f);
    o.w = fmaxf(acc[half * 4 + 3] * inv + bv.w, 0.f);
    *(float4*)&out[(size_t)n * 128 + f] = o;
  }
}

// ---------------------------------------------------------------------------
extern "C" void kernel_launch(void* const* d_in, const int* in_sizes, int n_in,
                              void* d_out, int out_size, void* d_ws, size_t ws_size,
                              hipStream_t stream) {
  const float* x = (const float*)d_in[0];
  const void* ei = d_in[1];
  const float* W = (const float*)d_in[2];
  const float* att_s = (const float*)d_in[3];
  const float* att_d = (const float*)d_in[4];
  const float* bias = (const float*)d_in[5];
  float* out = (float*)d_out;

  const int N = in_sizes[0] / 128;
  const int E = in_sizes[1] / 2;
  const int NB = (N + 255) >> 8;      // coarse buckets (<=512 for N<=131072)

  uint8_t* ws = (uint8_t*)d_ws;
  size_t off = 0;
  auto alloc = [&](size_t bytes) -> void* {
    void* p = ws + off;
    off = (off + bytes + 511) & ~(size_t)511;
    return p;
  };
  int* flag = (int*)alloc(4);
  int* bcur = (int*)alloc(512 * 4);
  unsigned short* Wt = (unsigned short*)alloc(128 * 128 * 2);
  int* offsets = (int*)alloc((size_t)(N + 1) * 4);
  uint32_t* fsr = (uint32_t*)alloc((size_t)E * 4);
  unsigned short* hb = (unsigned short*)alloc((size_t)N * 128 * 2);
  float* a_s = (float*)alloc((size_t)N * 4);
  float* a_d = (float*)alloc((size_t)N * 4);
  // Padded bucket scratch lives in d_out: dead until k_agg, which fully
  // rewrites out for every node afterwards (deterministic across replays).
  uint32_t* buck = (uint32_t*)d_out;   // NB*CAP*4 <= 17MB <= out 51.2MB
  (void)ws_size; (void)n_in; (void)out_size;

  const int ngemm = (N + 63) / 64;
  const int nms = (E + MS_CHUNK - 1) / MS_CHUNK;
  int grid = ngemm + nms;
  if (grid < 3 * nms - 2) grid = 3 * nms - 2;   // ms coverage: 3*(nms-1) < grid

  k_detect<<<1, 512, 0, stream>>>((const int*)ei, flag, bcur, W, Wt);
  k_fused<<<grid, 256, 0, stream>>>(x, Wt, att_s, att_d, hb, a_s, a_d, N,
                                    ei, flag, bcur, buck, E, nms);
  k_fine<<<NB, 1024, 0, stream>>>(bcur, buck, offsets, fsr, N, E);
  k_agg<<<(N + 3) / 4, 256, 0, stream>>>(offsets, fsr, a_s, a_d, hb, bias, out, N);
}